// Round 3
// baseline (883.468 us; speedup 1.0000x reference)
//
#include <hip/hip_runtime.h>
#include <math.h>

#define HID 256
#define NHEAD 8

// ---------------- GEMM: C[M x 256] = A[M x 256] @ W[256 x 256] (+ bias) ----
// 64x64 block tile, 256 threads, 4x4 micro-tile, BK=32 staged in LDS,
// register prefetch of the next K-tile during compute.
#define BM 64
#define BN 64
#define BK 32

__global__ __launch_bounds__(256) void gemm_f32(const float* __restrict__ A,
                                                const float* __restrict__ W,
                                                const float* __restrict__ bias,
                                                float* __restrict__ C, int M) {
    __shared__ float As[BK][BM + 4];  // transposed: As[k][m]; +4 keeps 16B alignment
    __shared__ float Bs[BK][BN + 4];
    const int tid  = threadIdx.x;
    const int row0 = blockIdx.x * BM;
    const int col0 = blockIdx.y * BN;
    const int tr = tid >> 4;        // 0..15 (rows tr*4..+3)
    const int tc = tid & 15;        // 0..15 (cols tc*4..+3)
    const int ar = tid >> 2;        // 0..63  A row
    const int ac = (tid & 3) * 8;   // 0,8,16,24  A col (2x float4)
    const int br = tid >> 3;        // 0..31  B row
    const int bc = (tid & 7) * 8;   // 0..56  B col (2x float4)
    const int arow = row0 + ar;

    float acc[4][4] = {};
    float4 a0, a1, b0, b1;

    // load first K-tile
    a0 = a1 = make_float4(0.f, 0.f, 0.f, 0.f);
    if (arow < M) {
        a0 = *(const float4*)&A[arow * HID + ac];
        a1 = *(const float4*)&A[arow * HID + ac + 4];
    }
    b0 = *(const float4*)&W[br * HID + col0 + bc];
    b1 = *(const float4*)&W[br * HID + col0 + bc + 4];

    for (int k0 = 0; k0 < HID; k0 += BK) {
        // store prefetched regs -> LDS
        As[ac + 0][ar] = a0.x; As[ac + 1][ar] = a0.y; As[ac + 2][ar] = a0.z; As[ac + 3][ar] = a0.w;
        As[ac + 4][ar] = a1.x; As[ac + 5][ar] = a1.y; As[ac + 6][ar] = a1.z; As[ac + 7][ar] = a1.w;
        *(float4*)&Bs[br][bc]     = b0;
        *(float4*)&Bs[br][bc + 4] = b1;
        __syncthreads();

        // prefetch next K-tile into regs (no LDS touch)
        const int kn = k0 + BK;
        if (kn < HID) {
            if (arow < M) {
                a0 = *(const float4*)&A[arow * HID + kn + ac];
                a1 = *(const float4*)&A[arow * HID + kn + ac + 4];
            }
            b0 = *(const float4*)&W[(kn + br) * HID + col0 + bc];
            b1 = *(const float4*)&W[(kn + br) * HID + col0 + bc + 4];
        }

#pragma unroll
        for (int kk = 0; kk < BK; ++kk) {
            const float4 av = *(const float4*)&As[kk][tr * 4];
            const float4 bv = *(const float4*)&Bs[kk][tc * 4];
            acc[0][0] += av.x * bv.x; acc[0][1] += av.x * bv.y; acc[0][2] += av.x * bv.z; acc[0][3] += av.x * bv.w;
            acc[1][0] += av.y * bv.x; acc[1][1] += av.y * bv.y; acc[1][2] += av.y * bv.z; acc[1][3] += av.y * bv.w;
            acc[2][0] += av.z * bv.x; acc[2][1] += av.z * bv.y; acc[2][2] += av.z * bv.z; acc[2][3] += av.z * bv.w;
            acc[3][0] += av.w * bv.x; acc[3][1] += av.w * bv.y; acc[3][2] += av.w * bv.z; acc[3][3] += av.w * bv.w;
        }
        __syncthreads();
    }

    float4 bia = make_float4(0.f, 0.f, 0.f, 0.f);
    if (bias) bia = *(const float4*)&bias[col0 + tc * 4];
#pragma unroll
    for (int i = 0; i < 4; ++i) {
        const int r = row0 + tr * 4 + i;
        if (r < M) {
            float4 o;
            o.x = acc[i][0] + bia.x;
            o.y = acc[i][1] + bia.y;
            o.z = acc[i][2] + bia.z;
            o.w = acc[i][3] + bia.w;
            *(float4*)&C[r * HID + col0 + tc * 4] = o;
        }
    }
}

// ---------------- small utility ----------------
__global__ void zero_kernel(int* __restrict__ p, int n) {
    int i = blockIdx.x * blockDim.x + threadIdx.x;
    if (i < n) p[i] = 0;
}

// ---------------- CSR build over dst ----------------
__global__ void histogram_kernel(const int* __restrict__ dst, int* __restrict__ counts, int E) {
    int e = blockIdx.x * blockDim.x + threadIdx.x;
    if (e < E) atomicAdd(&counts[dst[e]], 1);
}

// Single-block exclusive scan over n counts -> offsets[0..n], cursor[0..n-1]
__global__ __launch_bounds__(1024) void scan_kernel(const int* __restrict__ counts,
                                                    int* __restrict__ offsets,
                                                    int* __restrict__ cursor, int n) {
    __shared__ int warpsums[16];
    __shared__ int carry_s;
    const int tid  = threadIdx.x;
    const int lane = tid & 63;
    const int w    = tid >> 6;
    if (tid == 0) carry_s = 0;
    __syncthreads();
    for (int base = 0; base < n; base += 1024) {
        const int carry = carry_s;
        const int i = base + tid;
        const int x = (i < n) ? counts[i] : 0;
        int v = x;
#pragma unroll
        for (int d = 1; d < 64; d <<= 1) {
            int t = __shfl_up(v, d);
            if (lane >= d) v += t;
        }
        if (lane == 63) warpsums[w] = v;
        __syncthreads();
        if (tid < 16) {
            int s = warpsums[tid];
#pragma unroll
            for (int d = 1; d < 16; d <<= 1) {
                int t = __shfl_up(s, d);
                if (tid >= d) s += t;
            }
            warpsums[tid] = s;
        }
        __syncthreads();
        const int wprev = (w == 0) ? 0 : warpsums[w - 1];
        const int excl  = carry + wprev + (v - x);
        if (i < n) { offsets[i] = excl; cursor[i] = excl; }
        __syncthreads();
        if (tid == 0) carry_s = carry + warpsums[15];
        __syncthreads();
    }
    if (tid == 0) offsets[n] = carry_s;
}

__global__ void scatter_kernel(const int* __restrict__ src, const int* __restrict__ dst,
                               int* __restrict__ cursor, int* __restrict__ slot, int E) {
    int e = blockIdx.x * blockDim.x + threadIdx.x;
    if (e < E) {
        const int p = atomicAdd(&cursor[dst[e]], 1);
        slot[p] = src[e];
    }
}

// ---------------- per-dst-node attention aggregation ----------------
// One 64-lane wave per dst node. Lane owns 4 contiguous floats of the 256-wide
// row; head = lane/8. No atomics. o_pre may alias q (per-wave own-row only).
__global__ __launch_bounds__(256) void aggregate_kernel(const float* __restrict__ q,
                                                        const float* __restrict__ k,
                                                        const float* __restrict__ v,
                                                        const int* __restrict__ offsets,
                                                        const int* __restrict__ slot,
                                                        float* o_pre, int Ns) {
    const int wid  = blockIdx.x * 4 + (threadIdx.x >> 6);
    const int lane = threadIdx.x & 63;
    if (wid >= Ns) return;
    const int n = wid;

    const float4 q4 = *(const float4*)&q[(size_t)n * HID + lane * 4];
    float4 acc = make_float4(0.f, 0.f, 0.f, 0.f);
    float zacc = 0.f;
    const int e0 = offsets[n], e1 = offsets[n + 1];
    // score = exp(clamp(d/sqrt(32), -5, 5)) = exp2(clamp(d*C, -B, B))
    const float C = 0.25505416631923530f;  // (1/sqrt(32)) * log2(e)
    const float B = 7.2134752044448170f;   // 5 * log2(e)

    int e = e0;
    for (; e + 1 < e1; e += 2) {
        const int s0 = slot[e];
        const int s1 = slot[e + 1];
        const float4 k40 = *(const float4*)&k[(size_t)s0 * HID + lane * 4];
        const float4 v40 = *(const float4*)&v[(size_t)s0 * HID + lane * 4];
        const float4 k41 = *(const float4*)&k[(size_t)s1 * HID + lane * 4];
        const float4 v41 = *(const float4*)&v[(size_t)s1 * HID + lane * 4];
        float d0 = q4.x * k40.x + q4.y * k40.y + q4.z * k40.z + q4.w * k40.w;
        float d1 = q4.x * k41.x + q4.y * k41.y + q4.z * k41.z + q4.w * k41.w;
        d0 += __shfl_xor(d0, 1); d1 += __shfl_xor(d1, 1);
        d0 += __shfl_xor(d0, 2); d1 += __shfl_xor(d1, 2);
        d0 += __shfl_xor(d0, 4); d1 += __shfl_xor(d1, 4);
        float t0 = fminf(fmaxf(d0 * C, -B), B);
        float t1 = fminf(fmaxf(d1 * C, -B), B);
        const float sc0 = exp2f(t0);
        const float sc1 = exp2f(t1);
        acc.x += v40.x * sc0 + v41.x * sc1;
        acc.y += v40.y * sc0 + v41.y * sc1;
        acc.z += v40.z * sc0 + v41.z * sc1;
        acc.w += v40.w * sc0 + v41.w * sc1;
        zacc += sc0 + sc1;
    }
    if (e < e1) {
        const int s0 = slot[e];
        const float4 k40 = *(const float4*)&k[(size_t)s0 * HID + lane * 4];
        const float4 v40 = *(const float4*)&v[(size_t)s0 * HID + lane * 4];
        float d0 = q4.x * k40.x + q4.y * k40.y + q4.z * k40.z + q4.w * k40.w;
        d0 += __shfl_xor(d0, 1);
        d0 += __shfl_xor(d0, 2);
        d0 += __shfl_xor(d0, 4);
        float t0 = fminf(fmaxf(d0 * C, -B), B);
        const float sc0 = exp2f(t0);
        acc.x += v40.x * sc0;
        acc.y += v40.y * sc0;
        acc.z += v40.z * sc0;
        acc.w += v40.w * sc0;
        zacc += sc0;
    }
    const float inv_z = 1.0f / zacc;
    float4 o;
    o.x = acc.x * inv_z;
    o.y = acc.y * inv_z;
    o.z = acc.z * inv_z;
    o.w = acc.w * inv_z;
    *(float4*)&o_pre[(size_t)n * HID + lane * 4] = o;
}

extern "C" void kernel_launch(void* const* d_in, const int* in_sizes, int n_in,
                              void* d_out, int out_size, void* d_ws, size_t ws_size,
                              hipStream_t stream) {
    const float* context = (const float*)d_in[0];
    const float* node    = (const float*)d_in[1];
    const float* Wq      = (const float*)d_in[2];
    const float* bq      = (const float*)d_in[3];
    const float* Wk      = (const float*)d_in[4];
    const float* Wv      = (const float*)d_in[5];
    const float* Wo      = (const float*)d_in[6];
    const float* bo      = (const float*)d_in[7];
    const int*   src     = (const int*)d_in[8];
    const int*   dst     = (const int*)d_in[9];

    const int Nq = in_sizes[0] / HID;
    const int Ns = in_sizes[1] / HID;
    const int E  = in_sizes[8];
    float* out = (float*)d_out;

    // workspace layout (~157 MB): q doubles as o_pre after aggregation.
    float* q    = (float*)d_ws;                       // Ns*256 (reused as o_pre)
    float* kbuf = q + (size_t)Ns * HID;               // Nq*256
    float* vbuf = kbuf + (size_t)Nq * HID;            // Nq*256
    int* counts  = (int*)(vbuf + (size_t)Nq * HID);   // Ns
    int* offsets = counts + Ns;                       // Ns+1
    int* cursor  = offsets + Ns + 1;                  // Ns
    int* slot    = cursor + Ns;                       // E

    const dim3 blk(256);
    const dim3 gq((Ns + BM - 1) / BM, HID / BN);
    const dim3 gk((Nq + BM - 1) / BM, HID / BN);

    gemm_f32<<<gq, blk, 0, stream>>>(node, Wq, bq, q, Ns);
    gemm_f32<<<gk, blk, 0, stream>>>(context, Wk, nullptr, kbuf, Nq);
    gemm_f32<<<gk, blk, 0, stream>>>(context, Wv, nullptr, vbuf, Nq);

    zero_kernel<<<(Ns + 255) / 256, blk, 0, stream>>>(counts, Ns);
    histogram_kernel<<<(E + 255) / 256, blk, 0, stream>>>(dst, counts, E);
    scan_kernel<<<1, 1024, 0, stream>>>(counts, offsets, cursor, Ns);
    scatter_kernel<<<(E + 255) / 256, blk, 0, stream>>>(src, dst, cursor, slot, E);

    // o_pre aliases q (safe: per-wave read-own-row-then-write-own-row)
    aggregate_kernel<<<(Ns + 3) / 4, blk, 0, stream>>>(q, kbuf, vbuf, offsets, slot, q, Ns);

    gemm_f32<<<gq, blk, 0, stream>>>(q, Wo, bo, out, Ns);
}

// Round 5
// 797.877 us; speedup vs baseline: 1.1073x; 1.1073x over previous
//
#include <hip/hip_runtime.h>
#include <hip/hip_bf16.h>
#include <math.h>

#define HID 256

typedef __attribute__((ext_vector_type(8))) short bf16x8;
typedef __attribute__((ext_vector_type(4))) float f32x4;

__device__ __forceinline__ short f2bf(float x) {
    __hip_bfloat16 h = __float2bfloat16(x);
    union { __hip_bfloat16 b; short s; } u; u.b = h; return u.s;
}
__device__ __forceinline__ float bf2f(short s) {
    union { short s; __hip_bfloat16 b; } u; u.s = s; return __bfloat162float(u.b);
}

// ---------- W -> W^T split into hi/lo bf16 -------------------------------
// out layout per matrix m: hi at m*131072 + n*256 + k, lo at +65536.
__global__ __launch_bounds__(256) void convw_kernel(const float* __restrict__ W0,
                                                    const float* __restrict__ W1,
                                                    const float* __restrict__ W2,
                                                    short* __restrict__ outb) {
    const int m = blockIdx.x >> 8;
    const int n = blockIdx.x & 255;
    const int k = threadIdx.x;
    const float* W = (m == 0) ? W0 : (m == 1) ? W1 : W2;
    const float x = W[k * HID + n];
    const short hi = f2bf(x);
    const short lo = f2bf(x - bf2f(hi));
    short* o = outb + (size_t)m * 131072;
    o[n * HID + k] = hi;
    o[65536 + n * HID + k] = lo;
}

// ---------- GEMM via bf16x3 MFMA:  C[Mx256] = A[Mx256] @ W (+bias) -------
// Wt: split-bf16 W^T, hi at [n*256+k], lo at +65536. 64-row block, 4 waves
// (2M x 2N), wave tile 32x128, 16x16x32 MFMA, 3-term split accumulation.
__global__ __launch_bounds__(256) void gemm_mfma(const float* __restrict__ A,
                                                 const short* __restrict__ Wt,
                                                 const float* __restrict__ bias,
                                                 float* __restrict__ C, int M) {
    __shared__ short Ahi[64][56];   // 56-short row stride: 16B-aligned, ~2-way banks
    __shared__ short Alo[64][56];
    const int tid  = threadIdx.x;
    const int lane = tid & 63;
    const int wave = tid >> 6;
    const int wm = wave >> 1;       // 0..1  (M half)
    const int wn = wave & 1;        // 0..1  (N half)
    const int row0 = blockIdx.x * 64;

    const int srow = tid >> 2;          // 0..63 staging row
    const int scol = (tid & 3) * 8;     // 0,8,16,24
    const int arow = row0 + srow;
    const bool aok = arow < M;
    const float* aptr = A + (size_t)arow * HID + scol;

    f32x4 acc[2][8];
#pragma unroll
    for (int i = 0; i < 2; ++i)
#pragma unroll
        for (int j = 0; j < 8; ++j) acc[i][j] = (f32x4){0.f, 0.f, 0.f, 0.f};

    const int l15 = lane & 15;
    const int akk = (lane >> 4) * 8;
    const int arf = wm * 32 + l15;
    const short* wth = Wt + (size_t)(wn * 128 + l15) * HID + akk;
    const short* wtl = wth + 65536;

    // prefetch first A tile
    float4 x0 = make_float4(0.f, 0.f, 0.f, 0.f), x1 = x0;
    if (aok) { x0 = *(const float4*)(aptr); x1 = *(const float4*)(aptr + 4); }

    for (int k0 = 0; k0 < HID; k0 += 32) {
        __syncthreads();  // previous iteration's LDS reads complete
        {
            const float xs[8] = {x0.x, x0.y, x0.z, x0.w, x1.x, x1.y, x1.z, x1.w};
            bf16x8 hv, lv;
#pragma unroll
            for (int i = 0; i < 8; ++i) {
                const short h = f2bf(xs[i]);
                hv[i] = h;
                lv[i] = f2bf(xs[i] - bf2f(h));
            }
            *(bf16x8*)&Ahi[srow][scol] = hv;
            *(bf16x8*)&Alo[srow][scol] = lv;
        }
        __syncthreads();
        // prefetch next A tile during compute
        const int kn = k0 + 32;
        if (kn < HID && aok) {
            x0 = *(const float4*)(aptr + kn);
            x1 = *(const float4*)(aptr + kn + 4);
        }

        const bf16x8 ah0 = *(const bf16x8*)&Ahi[arf][akk];
        const bf16x8 ah1 = *(const bf16x8*)&Ahi[arf + 16][akk];
        const bf16x8 al0 = *(const bf16x8*)&Alo[arf][akk];
        const bf16x8 al1 = *(const bf16x8*)&Alo[arf + 16][akk];
#pragma unroll
        for (int ni = 0; ni < 8; ++ni) {
            const bf16x8 bh = *(const bf16x8*)(wth + (size_t)ni * 16 * HID + k0);
            const bf16x8 bl = *(const bf16x8*)(wtl + (size_t)ni * 16 * HID + k0);
            acc[0][ni] = __builtin_amdgcn_mfma_f32_16x16x32_bf16(ah0, bh, acc[0][ni], 0, 0, 0);
            acc[1][ni] = __builtin_amdgcn_mfma_f32_16x16x32_bf16(ah1, bh, acc[1][ni], 0, 0, 0);
            acc[0][ni] = __builtin_amdgcn_mfma_f32_16x16x32_bf16(al0, bh, acc[0][ni], 0, 0, 0);
            acc[1][ni] = __builtin_amdgcn_mfma_f32_16x16x32_bf16(al1, bh, acc[1][ni], 0, 0, 0);
            acc[0][ni] = __builtin_amdgcn_mfma_f32_16x16x32_bf16(ah0, bl, acc[0][ni], 0, 0, 0);
            acc[1][ni] = __builtin_amdgcn_mfma_f32_16x16x32_bf16(ah1, bl, acc[1][ni], 0, 0, 0);
        }
    }

    // epilogue: D lane mapping col=lane&15, row=(lane>>4)*4+j  [m89-verified]
    const int ccol0 = wn * 128 + l15;
    const int crow0 = row0 + wm * 32 + (lane >> 4) * 4;
#pragma unroll
    for (int ni = 0; ni < 8; ++ni) {
        const int col = ccol0 + ni * 16;
        const float b = bias ? bias[col] : 0.f;
#pragma unroll
        for (int mi = 0; mi < 2; ++mi) {
#pragma unroll
            for (int j = 0; j < 4; ++j) {
                const int r = crow0 + mi * 16 + j;
                if (r < M) C[(size_t)r * HID + col] = acc[mi][ni][j] + b;
            }
        }
    }
}

// ---------- small utility ----------
__global__ void zero_kernel(int* __restrict__ p, int n) {
    int i = blockIdx.x * blockDim.x + threadIdx.x;
    if (i < n) p[i] = 0;
}

// ---------- CSR build over dst ----------
__global__ void histogram_kernel(const int* __restrict__ dst, int* __restrict__ counts, int E) {
    int e = blockIdx.x * blockDim.x + threadIdx.x;
    if (e < E) atomicAdd(&counts[dst[e]], 1);
}

#define SCAN_B 1024
// per-block exclusive scan; block totals to bsums
__global__ __launch_bounds__(1024) void scan_local(const int* __restrict__ counts,
                                                   int* __restrict__ loc,
                                                   int* __restrict__ bsums, int n) {
    __shared__ int wsum[16];
    const int tid = threadIdx.x, lane = tid & 63, w = tid >> 6;
    const int i = blockIdx.x * SCAN_B + tid;
    const int x = (i < n) ? counts[i] : 0;
    int v = x;
#pragma unroll
    for (int d = 1; d < 64; d <<= 1) {
        int t = __shfl_up(v, d);
        if (lane >= d) v += t;
    }
    if (lane == 63) wsum[w] = v;
    __syncthreads();
    if (tid < 16) {
        int s = wsum[tid];
#pragma unroll
        for (int d = 1; d < 16; d <<= 1) {
            int t = __shfl_up(s, d);
            if (tid >= d) s += t;
        }
        wsum[tid] = s;
    }
    __syncthreads();
    const int excl = ((w == 0) ? 0 : wsum[w - 1]) + (v - x);
    if (i < n) loc[i] = excl;
    if (tid == SCAN_B - 1) bsums[blockIdx.x] = wsum[15];
}
// single-wave scan of block sums (nb <= 64); writes grand total to *total_out
__global__ void scan_bsums(int* __restrict__ bsums, int* __restrict__ total_out, int nb) {
    const int lane = threadIdx.x;
    const int x = (lane < nb) ? bsums[lane] : 0;
    int v = x;
#pragma unroll
    for (int d = 1; d < 64; d <<= 1) {
        int t = __shfl_up(v, d);
        if (lane >= d) v += t;
    }
    if (lane < nb) bsums[lane] = v - x;
    if (lane == 63) total_out[0] = v;
}
__global__ __launch_bounds__(1024) void scan_add(int* __restrict__ loc, const int* __restrict__ bsums,
                                                 int* __restrict__ cursor, int n) {
    const int i = blockIdx.x * SCAN_B + threadIdx.x;
    if (i < n) {
        const int o = loc[i] + bsums[blockIdx.x];
        loc[i] = o;       // loc == offsets (in place)
        cursor[i] = o;
    }
}

__global__ void scatter_kernel(const int* __restrict__ src, const int* __restrict__ dst,
                               int* __restrict__ cursor, int* __restrict__ slot, int E) {
    int e = blockIdx.x * blockDim.x + threadIdx.x;
    if (e < E) {
        const int p = atomicAdd(&cursor[dst[e]], 1);
        slot[p] = src[e];
    }
}

// ---------- per-dst-node attention aggregation (wave per node) ----------
__global__ __launch_bounds__(256) void aggregate_kernel(const float* __restrict__ q,
                                                        const float* __restrict__ k,
                                                        const float* __restrict__ v,
                                                        const int* __restrict__ offsets,
                                                        const int* __restrict__ slot,
                                                        float* o_pre, int Ns) {
    const int wid  = blockIdx.x * 4 + (threadIdx.x >> 6);
    const int lane = threadIdx.x & 63;
    if (wid >= Ns) return;
    const int n = wid;

    const float4 q4 = *(const float4*)&q[(size_t)n * HID + lane * 4];
    float4 acc = make_float4(0.f, 0.f, 0.f, 0.f);
    float zacc = 0.f;
    const int e0 = offsets[n], e1 = offsets[n + 1];
    const float Cc = 0.25505416631923530f;  // (1/sqrt(32)) * log2(e)
    const float Bb = 7.2134752044448170f;   // 5 * log2(e)

    int e = e0;
    for (; e + 3 < e1; e += 4) {
        const int s0 = slot[e], s1 = slot[e + 1], s2 = slot[e + 2], s3 = slot[e + 3];
        const float4 k40 = *(const float4*)&k[(size_t)s0 * HID + lane * 4];
        const float4 k41 = *(const float4*)&k[(size_t)s1 * HID + lane * 4];
        const float4 k42 = *(const float4*)&k[(size_t)s2 * HID + lane * 4];
        const float4 k43 = *(const float4*)&k[(size_t)s3 * HID + lane * 4];
        const float4 v40 = *(const float4*)&v[(size_t)s0 * HID + lane * 4];
        const float4 v41 = *(const float4*)&v[(size_t)s1 * HID + lane * 4];
        const float4 v42 = *(const float4*)&v[(size_t)s2 * HID + lane * 4];
        const float4 v43 = *(const float4*)&v[(size_t)s3 * HID + lane * 4];
        float d0 = q4.x * k40.x + q4.y * k40.y + q4.z * k40.z + q4.w * k40.w;
        float d1 = q4.x * k41.x + q4.y * k41.y + q4.z * k41.z + q4.w * k41.w;
        float d2 = q4.x * k42.x + q4.y * k42.y + q4.z * k42.z + q4.w * k42.w;
        float d3 = q4.x * k43.x + q4.y * k43.y + q4.z * k43.z + q4.w * k43.w;
        d0 += __shfl_xor(d0, 1); d1 += __shfl_xor(d1, 1); d2 += __shfl_xor(d2, 1); d3 += __shfl_xor(d3, 1);
        d0 += __shfl_xor(d0, 2); d1 += __shfl_xor(d1, 2); d2 += __shfl_xor(d2, 2); d3 += __shfl_xor(d3, 2);
        d0 += __shfl_xor(d0, 4); d1 += __shfl_xor(d1, 4); d2 += __shfl_xor(d2, 4); d3 += __shfl_xor(d3, 4);
        const float sc0 = exp2f(fminf(fmaxf(d0 * Cc, -Bb), Bb));
        const float sc1 = exp2f(fminf(fmaxf(d1 * Cc, -Bb), Bb));
        const float sc2 = exp2f(fminf(fmaxf(d2 * Cc, -Bb), Bb));
        const float sc3 = exp2f(fminf(fmaxf(d3 * Cc, -Bb), Bb));
        acc.x += v40.x * sc0 + v41.x * sc1 + v42.x * sc2 + v43.x * sc3;
        acc.y += v40.y * sc0 + v41.y * sc1 + v42.y * sc2 + v43.y * sc3;
        acc.z += v40.z * sc0 + v41.z * sc1 + v42.z * sc2 + v43.z * sc3;
        acc.w += v40.w * sc0 + v41.w * sc1 + v42.w * sc2 + v43.w * sc3;
        zacc += sc0 + sc1 + sc2 + sc3;
    }
    for (; e < e1; ++e) {
        const int s0 = slot[e];
        const float4 k40 = *(const float4*)&k[(size_t)s0 * HID + lane * 4];
        const float4 v40 = *(const float4*)&v[(size_t)s0 * HID + lane * 4];
        float d0 = q4.x * k40.x + q4.y * k40.y + q4.z * k40.z + q4.w * k40.w;
        d0 += __shfl_xor(d0, 1);
        d0 += __shfl_xor(d0, 2);
        d0 += __shfl_xor(d0, 4);
        const float sc0 = exp2f(fminf(fmaxf(d0 * Cc, -Bb), Bb));
        acc.x += v40.x * sc0;
        acc.y += v40.y * sc0;
        acc.z += v40.z * sc0;
        acc.w += v40.w * sc0;
        zacc += sc0;
    }
    const float inv_z = 1.0f / zacc;
    float4 o;
    o.x = acc.x * inv_z; o.y = acc.y * inv_z; o.z = acc.z * inv_z; o.w = acc.w * inv_z;
    *(float4*)&o_pre[(size_t)n * HID + lane * 4] = o;
}

extern "C" void kernel_launch(void* const* d_in, const int* in_sizes, int n_in,
                              void* d_out, int out_size, void* d_ws, size_t ws_size,
                              hipStream_t stream) {
    const float* context = (const float*)d_in[0];
    const float* node    = (const float*)d_in[1];
    const float* Wq      = (const float*)d_in[2];
    const float* bq      = (const float*)d_in[3];
    const float* Wk      = (const float*)d_in[4];
    const float* Wv      = (const float*)d_in[5];
    const float* Wo      = (const float*)d_in[6];
    const float* bo      = (const float*)d_in[7];
    const int*   src     = (const int*)d_in[8];
    const int*   dst     = (const int*)d_in[9];

    const int Nq = in_sizes[0] / HID;
    const int Ns = in_sizes[1] / HID;
    const int E  = in_sizes[8];
    float* out = (float*)d_out;

    // ---- workspace (same 157.4MB footprint as round 3) ----
    float* q    = (float*)d_ws;                       // Ns*256 (reused as o_pre)
    float* kbuf = q + (size_t)Ns * HID;               // Nq*256
    float* vbuf = kbuf + (size_t)Nq * HID;            // Nq*256
    int* counts  = (int*)(vbuf + (size_t)Nq * HID);   // Ns           (reused: cursor, then WtO)
    int* offsets = counts + Ns;                       // Ns+1 (+pad)  (loc/offsets; later part of WtO)
    int* bsums   = offsets + Ns + 8;                  // 64
    int* slot    = bsums + 64;                        // E            (first 768KB doubles as WtQKV)
    short* WtQKV = (short*)slot;                      // 3 * 131072 shorts (hi|lo per matrix)
    short* WtO   = (short*)counts;                    // 131072 shorts

    const dim3 blk(256);
    const int  gm = (Ns + 63) / 64;   // == (Nq+63)/64, Ns==Nq==50000
    const int  nb = (Ns + SCAN_B - 1) / SCAN_B;

    // 1. convert Wq,Wk,Wv -> split-bf16 W^T (lives in slot area, dead until scatter)
    convw_kernel<<<768, blk, 0, stream>>>(Wq, Wk, Wv, WtQKV);
    // 2-4. projections via bf16x3 MFMA
    gemm_mfma<<<gm, blk, 0, stream>>>(node,    WtQKV,          bq,      q,    Ns);
    gemm_mfma<<<gm, blk, 0, stream>>>(context, WtQKV + 131072, nullptr, kbuf, Nq);
    gemm_mfma<<<gm, blk, 0, stream>>>(context, WtQKV + 262144, nullptr, vbuf, Nq);
    // 5-8. CSR over dst
    zero_kernel<<<(Ns + 255) / 256, blk, 0, stream>>>(counts, Ns);
    histogram_kernel<<<(E + 255) / 256, blk, 0, stream>>>(dst, counts, E);
    scan_local<<<nb, SCAN_B, 0, stream>>>(counts, offsets, bsums, Ns);
    scan_bsums<<<1, 64, 0, stream>>>(bsums, offsets + Ns, nb);
    scan_add<<<nb, SCAN_B, 0, stream>>>(offsets, bsums, counts /*cursor*/, Ns);
    scatter_kernel<<<(E + 255) / 256, blk, 0, stream>>>(src, dst, counts /*cursor*/, slot, E);
    // 9. aggregation (o_pre aliases q: per-wave read-own-row-then-write-own-row)
    aggregate_kernel<<<(Ns + 3) / 4, blk, 0, stream>>>(q, kbuf, vbuf, offsets, slot, q, Ns);
    // 10. convert Wo (into dead counts/offsets area), 11. output projection
    convw_kernel<<<256, blk, 0, stream>>>(Wo, Wo, Wo, WtO);
    gemm_mfma<<<gm, blk, 0, stream>>>(q, WtO, bo, out, Ns);
}

// Round 6
// 763.014 us; speedup vs baseline: 1.1579x; 1.0457x over previous
//
#include <hip/hip_runtime.h>
#include <hip/hip_bf16.h>
#include <math.h>

#define HID 256

typedef __attribute__((ext_vector_type(8))) short bf16x8;
typedef __attribute__((ext_vector_type(4))) float f32x4;

__device__ __forceinline__ short f2bf(float x) {
    __hip_bfloat16 h = __float2bfloat16(x);
    union { __hip_bfloat16 b; short s; } u; u.b = h; return u.s;
}
__device__ __forceinline__ float bf2f(short s) {
    union { short s; __hip_bfloat16 b; } u; u.s = s; return __bfloat162float(u.b);
}

// ---------- W -> W^T split into hi/lo bf16 -------------------------------
// out layout per matrix m: hi at m*131072 + n*256 + k, lo at +65536.
__global__ __launch_bounds__(256) void convw_kernel(const float* __restrict__ W0,
                                                    const float* __restrict__ W1,
                                                    const float* __restrict__ W2,
                                                    short* __restrict__ outb) {
    const int m = blockIdx.x >> 8;
    const int n = blockIdx.x & 255;
    const int k = threadIdx.x;
    const float* W = (m == 0) ? W0 : (m == 1) ? W1 : W2;
    const float x = W[k * HID + n];
    const short hi = f2bf(x);
    const short lo = f2bf(x - bf2f(hi));
    short* o = outb + (size_t)m * 131072;
    o[n * HID + k] = hi;
    o[65536 + n * HID + k] = lo;
}

// ---------- GEMM via bf16x3 MFMA:  C[Mx256] = A[Mx256] @ W (+bias) -------
__global__ __launch_bounds__(256) void gemm_mfma(const float* __restrict__ A,
                                                 const short* __restrict__ Wt,
                                                 const float* __restrict__ bias,
                                                 float* __restrict__ C, int M) {
    __shared__ short Ahi[64][56];
    __shared__ short Alo[64][56];
    const int tid  = threadIdx.x;
    const int lane = tid & 63;
    const int wave = tid >> 6;
    const int wm = wave >> 1;
    const int wn = wave & 1;
    const int row0 = blockIdx.x * 64;

    const int srow = tid >> 2;
    const int scol = (tid & 3) * 8;
    const int arow = row0 + srow;
    const bool aok = arow < M;
    const float* aptr = A + (size_t)arow * HID + scol;

    f32x4 acc[2][8];
#pragma unroll
    for (int i = 0; i < 2; ++i)
#pragma unroll
        for (int j = 0; j < 8; ++j) acc[i][j] = (f32x4){0.f, 0.f, 0.f, 0.f};

    const int l15 = lane & 15;
    const int akk = (lane >> 4) * 8;
    const int arf = wm * 32 + l15;
    const short* wth = Wt + (size_t)(wn * 128 + l15) * HID + akk;
    const short* wtl = wth + 65536;

    float4 x0 = make_float4(0.f, 0.f, 0.f, 0.f), x1 = x0;
    if (aok) { x0 = *(const float4*)(aptr); x1 = *(const float4*)(aptr + 4); }

    for (int k0 = 0; k0 < HID; k0 += 32) {
        __syncthreads();
        {
            const float xs[8] = {x0.x, x0.y, x0.z, x0.w, x1.x, x1.y, x1.z, x1.w};
            bf16x8 hv, lv;
#pragma unroll
            for (int i = 0; i < 8; ++i) {
                const short h = f2bf(xs[i]);
                hv[i] = h;
                lv[i] = f2bf(xs[i] - bf2f(h));
            }
            *(bf16x8*)&Ahi[srow][scol] = hv;
            *(bf16x8*)&Alo[srow][scol] = lv;
        }
        __syncthreads();
        const int kn = k0 + 32;
        if (kn < HID && aok) {
            x0 = *(const float4*)(aptr + kn);
            x1 = *(const float4*)(aptr + kn + 4);
        }

        const bf16x8 ah0 = *(const bf16x8*)&Ahi[arf][akk];
        const bf16x8 ah1 = *(const bf16x8*)&Ahi[arf + 16][akk];
        const bf16x8 al0 = *(const bf16x8*)&Alo[arf][akk];
        const bf16x8 al1 = *(const bf16x8*)&Alo[arf + 16][akk];
#pragma unroll
        for (int ni = 0; ni < 8; ++ni) {
            const bf16x8 bh = *(const bf16x8*)(wth + (size_t)ni * 16 * HID + k0);
            const bf16x8 bl = *(const bf16x8*)(wtl + (size_t)ni * 16 * HID + k0);
            acc[0][ni] = __builtin_amdgcn_mfma_f32_16x16x32_bf16(ah0, bh, acc[0][ni], 0, 0, 0);
            acc[1][ni] = __builtin_amdgcn_mfma_f32_16x16x32_bf16(ah1, bh, acc[1][ni], 0, 0, 0);
            acc[0][ni] = __builtin_amdgcn_mfma_f32_16x16x32_bf16(al0, bh, acc[0][ni], 0, 0, 0);
            acc[1][ni] = __builtin_amdgcn_mfma_f32_16x16x32_bf16(al1, bh, acc[1][ni], 0, 0, 0);
            acc[0][ni] = __builtin_amdgcn_mfma_f32_16x16x32_bf16(ah0, bl, acc[0][ni], 0, 0, 0);
            acc[1][ni] = __builtin_amdgcn_mfma_f32_16x16x32_bf16(ah1, bl, acc[1][ni], 0, 0, 0);
        }
    }

    const int ccol0 = wn * 128 + l15;
    const int crow0 = row0 + wm * 32 + (lane >> 4) * 4;
#pragma unroll
    for (int ni = 0; ni < 8; ++ni) {
        const int col = ccol0 + ni * 16;
        const float b = bias ? bias[col] : 0.f;
#pragma unroll
        for (int mi = 0; mi < 2; ++mi) {
#pragma unroll
            for (int j = 0; j < 4; ++j) {
                const int r = crow0 + mi * 16 + j;
                if (r < M) C[(size_t)r * HID + col] = acc[mi][ni][j] + b;
            }
        }
    }
}

// ---------- fused K+V GEMM: one A staging feeds both weight matrices -----
__global__ __launch_bounds__(256) void gemm_mfma_kv(const float* __restrict__ A,
                                                    const short* __restrict__ WtK,
                                                    const short* __restrict__ WtV,
                                                    float* __restrict__ K,
                                                    float* __restrict__ V, int M) {
    __shared__ short Ahi[64][56];
    __shared__ short Alo[64][56];
    const int tid  = threadIdx.x;
    const int lane = tid & 63;
    const int wave = tid >> 6;
    const int wm = wave >> 1;
    const int wn = wave & 1;
    const int row0 = blockIdx.x * 64;

    const int srow = tid >> 2;
    const int scol = (tid & 3) * 8;
    const int arow = row0 + srow;
    const bool aok = arow < M;
    const float* aptr = A + (size_t)arow * HID + scol;

    f32x4 acck[2][8], accv[2][8];
#pragma unroll
    for (int i = 0; i < 2; ++i)
#pragma unroll
        for (int j = 0; j < 8; ++j) {
            acck[i][j] = (f32x4){0.f, 0.f, 0.f, 0.f};
            accv[i][j] = (f32x4){0.f, 0.f, 0.f, 0.f};
        }

    const int l15 = lane & 15;
    const int akk = (lane >> 4) * 8;
    const int arf = wm * 32 + l15;
    const size_t boff = (size_t)(wn * 128 + l15) * HID + akk;
    const short* wkh = WtK + boff;
    const short* wkl = wkh + 65536;
    const short* wvh = WtV + boff;
    const short* wvl = wvh + 65536;

    float4 x0 = make_float4(0.f, 0.f, 0.f, 0.f), x1 = x0;
    if (aok) { x0 = *(const float4*)(aptr); x1 = *(const float4*)(aptr + 4); }

    for (int k0 = 0; k0 < HID; k0 += 32) {
        __syncthreads();
        {
            const float xs[8] = {x0.x, x0.y, x0.z, x0.w, x1.x, x1.y, x1.z, x1.w};
            bf16x8 hv, lv;
#pragma unroll
            for (int i = 0; i < 8; ++i) {
                const short h = f2bf(xs[i]);
                hv[i] = h;
                lv[i] = f2bf(xs[i] - bf2f(h));
            }
            *(bf16x8*)&Ahi[srow][scol] = hv;
            *(bf16x8*)&Alo[srow][scol] = lv;
        }
        __syncthreads();
        const int kn = k0 + 32;
        if (kn < HID && aok) {
            x0 = *(const float4*)(aptr + kn);
            x1 = *(const float4*)(aptr + kn + 4);
        }

        const bf16x8 ah0 = *(const bf16x8*)&Ahi[arf][akk];
        const bf16x8 ah1 = *(const bf16x8*)&Ahi[arf + 16][akk];
        const bf16x8 al0 = *(const bf16x8*)&Alo[arf][akk];
        const bf16x8 al1 = *(const bf16x8*)&Alo[arf + 16][akk];
#pragma unroll
        for (int ni = 0; ni < 8; ++ni) {
            const size_t no = (size_t)ni * 16 * HID + k0;
            const bf16x8 bkh = *(const bf16x8*)(wkh + no);
            const bf16x8 bkl = *(const bf16x8*)(wkl + no);
            const bf16x8 bvh = *(const bf16x8*)(wvh + no);
            const bf16x8 bvl = *(const bf16x8*)(wvl + no);
            acck[0][ni] = __builtin_amdgcn_mfma_f32_16x16x32_bf16(ah0, bkh, acck[0][ni], 0, 0, 0);
            accv[0][ni] = __builtin_amdgcn_mfma_f32_16x16x32_bf16(ah0, bvh, accv[0][ni], 0, 0, 0);
            acck[1][ni] = __builtin_amdgcn_mfma_f32_16x16x32_bf16(ah1, bkh, acck[1][ni], 0, 0, 0);
            accv[1][ni] = __builtin_amdgcn_mfma_f32_16x16x32_bf16(ah1, bvh, accv[1][ni], 0, 0, 0);
            acck[0][ni] = __builtin_amdgcn_mfma_f32_16x16x32_bf16(al0, bkh, acck[0][ni], 0, 0, 0);
            accv[0][ni] = __builtin_amdgcn_mfma_f32_16x16x32_bf16(al0, bvh, accv[0][ni], 0, 0, 0);
            acck[1][ni] = __builtin_amdgcn_mfma_f32_16x16x32_bf16(al1, bkh, acck[1][ni], 0, 0, 0);
            accv[1][ni] = __builtin_amdgcn_mfma_f32_16x16x32_bf16(al1, bvh, accv[1][ni], 0, 0, 0);
            acck[0][ni] = __builtin_amdgcn_mfma_f32_16x16x32_bf16(ah0, bkl, acck[0][ni], 0, 0, 0);
            accv[0][ni] = __builtin_amdgcn_mfma_f32_16x16x32_bf16(ah0, bvl, accv[0][ni], 0, 0, 0);
            acck[1][ni] = __builtin_amdgcn_mfma_f32_16x16x32_bf16(ah1, bkl, acck[1][ni], 0, 0, 0);
            accv[1][ni] = __builtin_amdgcn_mfma_f32_16x16x32_bf16(ah1, bvl, accv[1][ni], 0, 0, 0);
        }
    }

    const int ccol0 = wn * 128 + l15;
    const int crow0 = row0 + wm * 32 + (lane >> 4) * 4;
#pragma unroll
    for (int ni = 0; ni < 8; ++ni) {
        const int col = ccol0 + ni * 16;
#pragma unroll
        for (int mi = 0; mi < 2; ++mi) {
#pragma unroll
            for (int j = 0; j < 4; ++j) {
                const int r = crow0 + mi * 16 + j;
                if (r < M) {
                    K[(size_t)r * HID + col] = acck[mi][ni][j];
                    V[(size_t)r * HID + col] = accv[mi][ni][j];
                }
            }
        }
    }
}

// ---------- small utility ----------
__global__ void zero_kernel(int* __restrict__ p, int n) {
    int i = blockIdx.x * blockDim.x + threadIdx.x;
    if (i < n) p[i] = 0;
}

// ---------- CSR build over dst ----------
__global__ void histogram_kernel(const int* __restrict__ dst, int* __restrict__ counts, int E) {
    int e = blockIdx.x * blockDim.x + threadIdx.x;
    if (e < E) atomicAdd(&counts[dst[e]], 1);
}

#define SCAN_B 1024
__global__ __launch_bounds__(1024) void scan_local(const int* __restrict__ counts,
                                                   int* __restrict__ loc,
                                                   int* __restrict__ bsums, int n) {
    __shared__ int wsum[16];
    const int tid = threadIdx.x, lane = tid & 63, w = tid >> 6;
    const int i = blockIdx.x * SCAN_B + tid;
    const int x = (i < n) ? counts[i] : 0;
    int v = x;
#pragma unroll
    for (int d = 1; d < 64; d <<= 1) {
        int t = __shfl_up(v, d);
        if (lane >= d) v += t;
    }
    if (lane == 63) wsum[w] = v;
    __syncthreads();
    if (tid < 16) {
        int s = wsum[tid];
#pragma unroll
        for (int d = 1; d < 16; d <<= 1) {
            int t = __shfl_up(s, d);
            if (tid >= d) s += t;
        }
        wsum[tid] = s;
    }
    __syncthreads();
    const int excl = ((w == 0) ? 0 : wsum[w - 1]) + (v - x);
    if (i < n) loc[i] = excl;
    if (tid == SCAN_B - 1) bsums[blockIdx.x] = wsum[15];
}
__global__ void scan_bsums(int* __restrict__ bsums, int* __restrict__ total_out, int nb) {
    const int lane = threadIdx.x;
    const int x = (lane < nb) ? bsums[lane] : 0;
    int v = x;
#pragma unroll
    for (int d = 1; d < 64; d <<= 1) {
        int t = __shfl_up(v, d);
        if (lane >= d) v += t;
    }
    if (lane < nb) bsums[lane] = v - x;
    if (lane == 63) total_out[0] = v;
}
__global__ __launch_bounds__(1024) void scan_add(int* __restrict__ loc, const int* __restrict__ bsums,
                                                 int* __restrict__ cursor, int n) {
    const int i = blockIdx.x * SCAN_B + threadIdx.x;
    if (i < n) {
        const int o = loc[i] + bsums[blockIdx.x];
        loc[i] = o;
        cursor[i] = o;
    }
}

__global__ void scatter_kernel(const int* __restrict__ src, const int* __restrict__ dst,
                               int* __restrict__ cursor, int* __restrict__ slot, int E) {
    int e = blockIdx.x * blockDim.x + threadIdx.x;
    if (e < E) {
        const int p = atomicAdd(&cursor[dst[e]], 1);
        slot[p] = src[e];
    }
}

// ---------- per-dst-node attention aggregation (wave per node) ----------
// Register-pipelined: one coalesced slot load per 64-edge chunk, indices
// distributed by shfl; rotating double-buffered quads (16 float4 in flight).
__global__ __launch_bounds__(256) void aggregate_kernel(const float* __restrict__ q,
                                                        const float* __restrict__ k,
                                                        const float* __restrict__ v,
                                                        const int* __restrict__ offsets,
                                                        const int* __restrict__ slot,
                                                        float* o_pre, int Ns) {
    const int n    = blockIdx.x * 4 + (threadIdx.x >> 6);
    const int lane = threadIdx.x & 63;
    if (n >= Ns) return;

    const float4 q4 = *(const float4*)&q[(size_t)n * HID + lane * 4];
    const int e0 = offsets[n], e1 = offsets[n + 1];
    float4 acc = make_float4(0.f, 0.f, 0.f, 0.f);
    float zacc = 0.f;
    const float Cc = 0.25505416631923530f;  // (1/sqrt(32)) * log2(e)
    const float Bb = 7.2134752044448170f;   // 5 * log2(e)

    for (int base = e0; base < e1; base += 64) {
        const int chunk = (e1 - base < 64) ? (e1 - base) : 64;
        const int li = (lane < chunk) ? lane : (chunk - 1);
        const int sv = slot[base + li];

        float4 ka[4], va[4], kb[4], vb[4];
        int sa[4], sb[4];
#pragma unroll
        for (int i = 0; i < 4; ++i) {
            sa[i] = __shfl(sv, (0 + i < chunk) ? (0 + i) : 0);
            sb[i] = __shfl(sv, (4 + i < chunk) ? (4 + i) : 0);
        }
#pragma unroll
        for (int i = 0; i < 4; ++i) {
            ka[i] = *(const float4*)&k[(size_t)sa[i] * HID + lane * 4];
            va[i] = *(const float4*)&v[(size_t)sa[i] * HID + lane * 4];
        }
#pragma unroll
        for (int i = 0; i < 4; ++i) {
            kb[i] = *(const float4*)&k[(size_t)sb[i] * HID + lane * 4];
            vb[i] = *(const float4*)&v[(size_t)sb[i] * HID + lane * 4];
        }

        for (int j = 0; j < chunk; j += 8) {
            // ---- compute quad A (edges j..j+3) ----
            {
                float d[4];
#pragma unroll
                for (int i = 0; i < 4; ++i)
                    d[i] = q4.x * ka[i].x + q4.y * ka[i].y + q4.z * ka[i].z + q4.w * ka[i].w;
#pragma unroll
                for (int i = 0; i < 4; ++i) {
                    d[i] += __shfl_xor(d[i], 1);
                    d[i] += __shfl_xor(d[i], 2);
                    d[i] += __shfl_xor(d[i], 4);
                }
#pragma unroll
                for (int i = 0; i < 4; ++i) {
                    float sc = exp2f(fminf(fmaxf(d[i] * Cc, -Bb), Bb));
                    sc = (j + i < chunk) ? sc : 0.f;
                    acc.x += va[i].x * sc; acc.y += va[i].y * sc;
                    acc.z += va[i].z * sc; acc.w += va[i].w * sc;
                    zacc += sc;
                }
            }
            // ---- refill A with quad j+8 ----
            if (j + 8 < chunk) {
#pragma unroll
                for (int i = 0; i < 4; ++i)
                    sa[i] = __shfl(sv, (j + 8 + i < chunk) ? (j + 8 + i) : 0);
#pragma unroll
                for (int i = 0; i < 4; ++i) {
                    ka[i] = *(const float4*)&k[(size_t)sa[i] * HID + lane * 4];
                    va[i] = *(const float4*)&v[(size_t)sa[i] * HID + lane * 4];
                }
            }
            // ---- compute quad B (edges j+4..j+7) ----
            {
                float d[4];
#pragma unroll
                for (int i = 0; i < 4; ++i)
                    d[i] = q4.x * kb[i].x + q4.y * kb[i].y + q4.z * kb[i].z + q4.w * kb[i].w;
#pragma unroll
                for (int i = 0; i < 4; ++i) {
                    d[i] += __shfl_xor(d[i], 1);
                    d[i] += __shfl_xor(d[i], 2);
                    d[i] += __shfl_xor(d[i], 4);
                }
#pragma unroll
                for (int i = 0; i < 4; ++i) {
                    float sc = exp2f(fminf(fmaxf(d[i] * Cc, -Bb), Bb));
                    sc = (j + 4 + i < chunk) ? sc : 0.f;
                    acc.x += vb[i].x * sc; acc.y += vb[i].y * sc;
                    acc.z += vb[i].z * sc; acc.w += vb[i].w * sc;
                    zacc += sc;
                }
            }
            // ---- refill B with quad j+12 ----
            if (j + 12 < chunk) {
#pragma unroll
                for (int i = 0; i < 4; ++i)
                    sb[i] = __shfl(sv, (j + 12 + i < chunk) ? (j + 12 + i) : 0);
#pragma unroll
                for (int i = 0; i < 4; ++i) {
                    kb[i] = *(const float4*)&k[(size_t)sb[i] * HID + lane * 4];
                    vb[i] = *(const float4*)&v[(size_t)sb[i] * HID + lane * 4];
                }
            }
        }
    }

    const float inv_z = 1.0f / zacc;
    float4 o;
    o.x = acc.x * inv_z; o.y = acc.y * inv_z; o.z = acc.z * inv_z; o.w = acc.w * inv_z;
    *(float4*)&o_pre[(size_t)n * HID + lane * 4] = o;
}

extern "C" void kernel_launch(void* const* d_in, const int* in_sizes, int n_in,
                              void* d_out, int out_size, void* d_ws, size_t ws_size,
                              hipStream_t stream) {
    const float* context = (const float*)d_in[0];
    const float* node    = (const float*)d_in[1];
    const float* Wq      = (const float*)d_in[2];
    const float* bq      = (const float*)d_in[3];
    const float* Wk      = (const float*)d_in[4];
    const float* Wv      = (const float*)d_in[5];
    const float* Wo      = (const float*)d_in[6];
    const float* bo      = (const float*)d_in[7];
    const int*   src     = (const int*)d_in[8];
    const int*   dst     = (const int*)d_in[9];

    const int Nq = in_sizes[0] / HID;
    const int Ns = in_sizes[1] / HID;
    const int E  = in_sizes[8];
    float* out = (float*)d_out;

    // ---- workspace (same 157.4MB footprint as round 3/5) ----
    float* q    = (float*)d_ws;                       // Ns*256 (reused as o_pre)
    float* kbuf = q + (size_t)Ns * HID;               // Nq*256
    float* vbuf = kbuf + (size_t)Nq * HID;            // Nq*256
    int* counts  = (int*)(vbuf + (size_t)Nq * HID);   // Ns           (reused: cursor, then WtO)
    int* offsets = counts + Ns;                       // Ns+1 (+pad)
    int* bsums   = offsets + Ns + 8;                  // 64
    int* slot    = bsums + 64;                        // E  (first 768KB doubles as WtQKV)
    short* WtQKV = (short*)slot;                      // 3 * 131072 shorts
    short* WtO   = (short*)counts;                    // 131072 shorts

    const dim3 blk(256);
    const int  gm = (Ns + 63) / 64;
    const int  nb = (Ns + SCAN_B - 1) / SCAN_B;

    convw_kernel<<<768, blk, 0, stream>>>(Wq, Wk, Wv, WtQKV);
    gemm_mfma<<<gm, blk, 0, stream>>>(node, WtQKV, bq, q, Ns);
    gemm_mfma_kv<<<gm, blk, 0, stream>>>(context, WtQKV + 131072, WtQKV + 262144, kbuf, vbuf, Nq);

    zero_kernel<<<(Ns + 255) / 256, blk, 0, stream>>>(counts, Ns);
    histogram_kernel<<<(E + 255) / 256, blk, 0, stream>>>(dst, counts, E);
    scan_local<<<nb, SCAN_B, 0, stream>>>(counts, offsets, bsums, Ns);
    scan_bsums<<<1, 64, 0, stream>>>(bsums, offsets + Ns, nb);
    scan_add<<<nb, SCAN_B, 0, stream>>>(offsets, bsums, counts /*cursor*/, Ns);
    scatter_kernel<<<(E + 255) / 256, blk, 0, stream>>>(src, dst, counts /*cursor*/, slot, E);

    aggregate_kernel<<<(Ns + 3) / 4, blk, 0, stream>>>(q, kbuf, vbuf, offsets, slot, q, Ns);

    convw_kernel<<<256, blk, 0, stream>>>(Wo, Wo, Wo, WtO);
    gemm_mfma<<<gm, blk, 0, stream>>>(q, WtO, bo, out, Ns);
}

// Round 8
// 498.286 us; speedup vs baseline: 1.7730x; 1.5313x over previous
//
#include <hip/hip_runtime.h>
#include <hip/hip_bf16.h>
#include <math.h>

#define HID 256

typedef __attribute__((ext_vector_type(8))) short bf16x8;
typedef __attribute__((ext_vector_type(4))) float f32x4;

__device__ __forceinline__ short f2bf(float x) {
    __hip_bfloat16 h = __float2bfloat16(x);
    union { __hip_bfloat16 b; short s; } u; u.b = h; return u.s;
}
__device__ __forceinline__ float bf2f(short s) {
    union { short s; __hip_bfloat16 b; } u; u.s = s; return __bfloat162float(u.b);
}

// ---------- W -> W^T split into hi/lo bf16 -------------------------------
// out layout per matrix m: hi at m*131072 + n*256 + k, lo at +65536.
__global__ __launch_bounds__(256) void convw_kernel(const float* __restrict__ W0,
                                                    const float* __restrict__ W1,
                                                    const float* __restrict__ W2,
                                                    short* __restrict__ outb) {
    const int m = blockIdx.x >> 8;
    const int n = blockIdx.x & 255;
    const int k = threadIdx.x;
    const float* W = (m == 0) ? W0 : (m == 1) ? W1 : W2;
    const float x = W[k * HID + n];
    const short hi = f2bf(x);
    const short lo = f2bf(x - bf2f(hi));
    short* o = outb + (size_t)m * 131072;
    o[n * HID + k] = hi;
    o[65536 + n * HID + k] = lo;
}

// ---------- GEMM via bf16x3 MFMA, A+B LDS-staged -------------------------
// C[Mx256] = A[Mx256] @ W. 128-row block, 512 threads = 8 waves (4M x 2N),
// wave tile 32x128, 16x16x32 MFMA, 3-term split accumulation.
// Output: Cf fp32 (+bias)  OR  kvout bf16 interleaved kv rows (part 0=k,1=v).
// LDS rows of 40 shorts (80B): 2-way bank aliasing only (free), 16B-aligned.
__global__ __launch_bounds__(512, 4) void gemm_mfma(const float* __restrict__ A,
                                                    const short* __restrict__ Wt,
                                                    const float* __restrict__ bias,
                                                    float* __restrict__ Cf,
                                                    short* __restrict__ kvout,
                                                    int part, int M) {
    __shared__ short Ahi[128][40];
    __shared__ short Alo[128][40];
    __shared__ short Bhi[256][40];
    __shared__ short Blo[256][40];
    const int tid  = threadIdx.x;
    const int lane = tid & 63;
    const int wave = tid >> 6;      // 0..7
    const int wm   = wave >> 1;     // 0..3 (M quarter)
    const int wn   = wave & 1;      // 0..1 (N half)
    const int row0 = blockIdx.x * 128;

    // A staging: thread covers 8 k of one row
    const int srow = tid >> 2;          // 0..127
    const int scol = (tid & 3) * 8;     // 0,8,16,24
    const int arow = row0 + srow;
    const bool aok = arow < M;
    const float* aptr = A + (size_t)arow * HID + scol;

    // B staging: thread covers 16 k of one col (hi and lo)
    const int bn = tid >> 1;            // 0..255
    const int bk = (tid & 1) * 16;      // 0,16
    const short* bhp = Wt + bn * HID + bk;
    const short* blp = bhp + 65536;

    f32x4 acc[2][8];
#pragma unroll
    for (int i = 0; i < 2; ++i)
#pragma unroll
        for (int j = 0; j < 8; ++j) acc[i][j] = (f32x4){0.f, 0.f, 0.f, 0.f};

    const int l15 = lane & 15;
    const int akk = (lane >> 4) * 8;    // 0,8,16,24

    // prefetch first K-tile into regs
    float4 x0 = make_float4(0.f, 0.f, 0.f, 0.f), x1 = x0;
    if (aok) { x0 = *(const float4*)(aptr); x1 = *(const float4*)(aptr + 4); }
    bf16x8 pb0 = *(const bf16x8*)(bhp);
    bf16x8 pb1 = *(const bf16x8*)(bhp + 8);
    bf16x8 pb2 = *(const bf16x8*)(blp);
    bf16x8 pb3 = *(const bf16x8*)(blp + 8);

    for (int k0 = 0; k0 < HID; k0 += 32) {
        __syncthreads();    // prior iteration's LDS reads complete
        {
            const float xs[8] = {x0.x, x0.y, x0.z, x0.w, x1.x, x1.y, x1.z, x1.w};
            bf16x8 hv, lv;
#pragma unroll
            for (int i = 0; i < 8; ++i) {
                const short h = f2bf(xs[i]);
                hv[i] = h;
                lv[i] = f2bf(xs[i] - bf2f(h));
            }
            *(bf16x8*)&Ahi[srow][scol] = hv;
            *(bf16x8*)&Alo[srow][scol] = lv;
        }
        *(bf16x8*)&Bhi[bn][bk]     = pb0;
        *(bf16x8*)&Bhi[bn][bk + 8] = pb1;
        *(bf16x8*)&Blo[bn][bk]     = pb2;
        *(bf16x8*)&Blo[bn][bk + 8] = pb3;
        __syncthreads();
        // prefetch next K-tile during compute
        const int kn = k0 + 32;
        if (kn < HID) {
            if (aok) { x0 = *(const float4*)(aptr + kn); x1 = *(const float4*)(aptr + kn + 4); }
            pb0 = *(const bf16x8*)(bhp + kn);
            pb1 = *(const bf16x8*)(bhp + kn + 8);
            pb2 = *(const bf16x8*)(blp + kn);
            pb3 = *(const bf16x8*)(blp + kn + 8);
        }

        const bf16x8 ah0 = *(const bf16x8*)&Ahi[wm * 32 + l15][akk];
        const bf16x8 ah1 = *(const bf16x8*)&Ahi[wm * 32 + 16 + l15][akk];
        const bf16x8 al0 = *(const bf16x8*)&Alo[wm * 32 + l15][akk];
        const bf16x8 al1 = *(const bf16x8*)&Alo[wm * 32 + 16 + l15][akk];
#pragma unroll
        for (int ni = 0; ni < 8; ++ni) {
            const int col = wn * 128 + ni * 16 + l15;
            const bf16x8 bh = *(const bf16x8*)&Bhi[col][akk];
            const bf16x8 bl = *(const bf16x8*)&Blo[col][akk];
            acc[0][ni] = __builtin_amdgcn_mfma_f32_16x16x32_bf16(ah0, bh, acc[0][ni], 0, 0, 0);
            acc[1][ni] = __builtin_amdgcn_mfma_f32_16x16x32_bf16(ah1, bh, acc[1][ni], 0, 0, 0);
            acc[0][ni] = __builtin_amdgcn_mfma_f32_16x16x32_bf16(al0, bh, acc[0][ni], 0, 0, 0);
            acc[1][ni] = __builtin_amdgcn_mfma_f32_16x16x32_bf16(al1, bh, acc[1][ni], 0, 0, 0);
            acc[0][ni] = __builtin_amdgcn_mfma_f32_16x16x32_bf16(ah0, bl, acc[0][ni], 0, 0, 0);
            acc[1][ni] = __builtin_amdgcn_mfma_f32_16x16x32_bf16(ah1, bl, acc[1][ni], 0, 0, 0);
        }
    }

    // epilogue: D lane mapping col=lane&15, row=(lane>>4)*4+j  [m89-verified]
    const int ccol0 = wn * 128 + l15;
    const int crow0 = row0 + wm * 32 + (lane >> 4) * 4;
    if (Cf) {
#pragma unroll
        for (int ni = 0; ni < 8; ++ni) {
            const int col = ccol0 + ni * 16;
            const float b = bias ? bias[col] : 0.f;
#pragma unroll
            for (int mi = 0; mi < 2; ++mi) {
#pragma unroll
                for (int j = 0; j < 4; ++j) {
                    const int r = crow0 + mi * 16 + j;
                    if (r < M) Cf[(size_t)r * HID + col] = acc[mi][ni][j] + b;
                }
            }
        }
    } else {
        // kv row (512 shorts): group g: [k4g..k4g+3 | v4g..v4g+3]
#pragma unroll
        for (int ni = 0; ni < 8; ++ni) {
            const int col = ccol0 + ni * 16;
            const int off = (col >> 2) * 8 + (col & 3) + part * 4;
#pragma unroll
            for (int mi = 0; mi < 2; ++mi) {
#pragma unroll
                for (int j = 0; j < 4; ++j) {
                    const int r = crow0 + mi * 16 + j;
                    if (r < M) kvout[(size_t)r * 512 + off] = f2bf(acc[mi][ni][j]);
                }
            }
        }
    }
}

// ---------- small utility ----------
__global__ void zero_kernel(int* __restrict__ p, int n) {
    int i = blockIdx.x * blockDim.x + threadIdx.x;
    if (i < n) p[i] = 0;
}

// ---------- CSR build over dst ----------
__global__ void histogram_kernel(const int* __restrict__ dst, int* __restrict__ counts, int E) {
    int e = blockIdx.x * blockDim.x + threadIdx.x;
    if (e < E) atomicAdd(&counts[dst[e]], 1);
}

#define SCAN_B 1024
__global__ __launch_bounds__(1024) void scan_local(const int* __restrict__ counts,
                                                   int* __restrict__ loc,
                                                   int* __restrict__ bsums, int n) {
    __shared__ int wsum[16];
    const int tid = threadIdx.x, lane = tid & 63, w = tid >> 6;
    const int i = blockIdx.x * SCAN_B + tid;
    const int x = (i < n) ? counts[i] : 0;
    int v = x;
#pragma unroll
    for (int d = 1; d < 64; d <<= 1) {
        int t = __shfl_up(v, d);
        if (lane >= d) v += t;
    }
    if (lane == 63) wsum[w] = v;
    __syncthreads();
    if (tid < 16) {
        int s = wsum[tid];
#pragma unroll
        for (int d = 1; d < 16; d <<= 1) {
            int t = __shfl_up(s, d);
            if (tid >= d) s += t;
        }
        wsum[tid] = s;
    }
    __syncthreads();
    const int excl = ((w == 0) ? 0 : wsum[w - 1]) + (v - x);
    if (i < n) loc[i] = excl;
    if (tid == SCAN_B - 1) bsums[blockIdx.x] = wsum[15];
}
__global__ void scan_bsums(int* __restrict__ bsums, int* __restrict__ total_out, int nb) {
    const int lane = threadIdx.x;
    const int x = (lane < nb) ? bsums[lane] : 0;
    int v = x;
#pragma unroll
    for (int d = 1; d < 64; d <<= 1) {
        int t = __shfl_up(v, d);
        if (lane >= d) v += t;
    }
    if (lane < nb) bsums[lane] = v - x;
    if (lane == 63) total_out[0] = v;
}
__global__ __launch_bounds__(1024) void scan_add(int* __restrict__ loc, const int* __restrict__ bsums,
                                                 int* __restrict__ cursor, int n) {
    const int i = blockIdx.x * SCAN_B + threadIdx.x;
    if (i < n) {
        const int o = loc[i] + bsums[blockIdx.x];
        loc[i] = o;
        cursor[i] = o;
    }
}

__global__ void scatter_kernel(const int* __restrict__ src, const int* __restrict__ dst,
                               int* __restrict__ cursor, int* __restrict__ slot, int E) {
    int e = blockIdx.x * blockDim.x + threadIdx.x;
    if (e < E) {
        const int p = atomicAdd(&cursor[dst[e]], 1);
        slot[p] = src[e];
    }
}

// ---------- per-dst-node attention aggregation (wave per node) ----------
// bf16 packed kv: per edge, ONE contiguous 1KB wave read (16B/lane:
// lane g gets k[4g..4g+3] ++ v[4g..4g+3]). Register-pipelined quads.
__global__ __launch_bounds__(256) void aggregate_kernel(const float* __restrict__ q,
                                                        const short* __restrict__ kv,
                                                        const int* __restrict__ offsets,
                                                        const int* __restrict__ slot,
                                                        float* o_pre, int Ns) {
    const int n    = blockIdx.x * 4 + (threadIdx.x >> 6);
    const int lane = threadIdx.x & 63;
    if (n >= Ns) return;

    const float4 q4 = *(const float4*)&q[(size_t)n * HID + lane * 4];
    const int e0 = offsets[n], e1 = offsets[n + 1];
    float4 acc = make_float4(0.f, 0.f, 0.f, 0.f);
    float zacc = 0.f;
    const float Cc = 0.25505416631923530f;  // (1/sqrt(32)) * log2(e)
    const float Bb = 7.2134752044448170f;   // 5 * log2(e)
    const size_t loff = (size_t)lane * 8;

    for (int base = e0; base < e1; base += 64) {
        const int chunk = (e1 - base < 64) ? (e1 - base) : 64;
        const int li = (lane < chunk) ? lane : (chunk - 1);
        const int sv = slot[base + li];

        bf16x8 ga[4], gb[4];
        int sa[4], sb[4];
#pragma unroll
        for (int i = 0; i < 4; ++i) {
            sa[i] = __shfl(sv, (0 + i < chunk) ? (0 + i) : 0);
            sb[i] = __shfl(sv, (4 + i < chunk) ? (4 + i) : 0);
        }
#pragma unroll
        for (int i = 0; i < 4; ++i) ga[i] = *(const bf16x8*)(kv + (size_t)sa[i] * 512 + loff);
#pragma unroll
        for (int i = 0; i < 4; ++i) gb[i] = *(const bf16x8*)(kv + (size_t)sb[i] * 512 + loff);

        for (int j = 0; j < chunk; j += 8) {
            // ---- compute quad A (edges j..j+3) ----
            {
                float d[4];
#pragma unroll
                for (int i = 0; i < 4; ++i)
                    d[i] = q4.x * bf2f(ga[i][0]) + q4.y * bf2f(ga[i][1]) +
                           q4.z * bf2f(ga[i][2]) + q4.w * bf2f(ga[i][3]);
#pragma unroll
                for (int i = 0; i < 4; ++i) {
                    d[i] += __shfl_xor(d[i], 1);
                    d[i] += __shfl_xor(d[i], 2);
                    d[i] += __shfl_xor(d[i], 4);
                }
#pragma unroll
                for (int i = 0; i < 4; ++i) {
                    float sc = exp2f(fminf(fmaxf(d[i] * Cc, -Bb), Bb));
                    sc = (j + i < chunk) ? sc : 0.f;
                    acc.x += bf2f(ga[i][4]) * sc; acc.y += bf2f(ga[i][5]) * sc;
                    acc.z += bf2f(ga[i][6]) * sc; acc.w += bf2f(ga[i][7]) * sc;
                    zacc += sc;
                }
            }
            // ---- refill A with quad j+8 ----
            if (j + 8 < chunk) {
#pragma unroll
                for (int i = 0; i < 4; ++i)
                    sa[i] = __shfl(sv, (j + 8 + i < chunk) ? (j + 8 + i) : 0);
#pragma unroll
                for (int i = 0; i < 4; ++i) ga[i] = *(const bf16x8*)(kv + (size_t)sa[i] * 512 + loff);
            }
            // ---- compute quad B (edges j+4..j+7) ----
            {
                float d[4];
#pragma unroll
                for (int i = 0; i < 4; ++i)
                    d[i] = q4.x * bf2f(gb[i][0]) + q4.y * bf2f(gb[i][1]) +
                           q4.z * bf2f(gb[i][2]) + q4.w * bf2f(gb[i][3]);
#pragma unroll
                for (int i = 0; i < 4; ++i) {
                    d[i] += __shfl_xor(d[i], 1);
                    d[i] += __shfl_xor(d[i], 2);
                    d[i] += __shfl_xor(d[i], 4);
                }
#pragma unroll
                for (int i = 0; i < 4; ++i) {
                    float sc = exp2f(fminf(fmaxf(d[i] * Cc, -Bb), Bb));
                    sc = (j + 4 + i < chunk) ? sc : 0.f;
                    acc.x += bf2f(gb[i][4]) * sc; acc.y += bf2f(gb[i][5]) * sc;
                    acc.z += bf2f(gb[i][6]) * sc; acc.w += bf2f(gb[i][7]) * sc;
                    zacc += sc;
                }
            }
            // ---- refill B with quad j+12 ----
            if (j + 12 < chunk) {
#pragma unroll
                for (int i = 0; i < 4; ++i)
                    sb[i] = __shfl(sv, (j + 12 + i < chunk) ? (j + 12 + i) : 0);
#pragma unroll
                for (int i = 0; i < 4; ++i) gb[i] = *(const bf16x8*)(kv + (size_t)sb[i] * 512 + loff);
            }
        }
    }

    const float inv_z = 1.0f / zacc;
    float4 o;
    o.x = acc.x * inv_z; o.y = acc.y * inv_z; o.z = acc.z * inv_z; o.w = acc.w * inv_z;
    *(float4*)&o_pre[(size_t)n * HID + lane * 4] = o;
}

extern "C" void kernel_launch(void* const* d_in, const int* in_sizes, int n_in,
                              void* d_out, int out_size, void* d_ws, size_t ws_size,
                              hipStream_t stream) {
    const float* context = (const float*)d_in[0];
    const float* node    = (const float*)d_in[1];
    const float* Wq      = (const float*)d_in[2];
    const float* bq      = (const float*)d_in[3];
    const float* Wk      = (const float*)d_in[4];
    const float* Wv      = (const float*)d_in[5];
    const float* Wo      = (const float*)d_in[6];
    const float* bo      = (const float*)d_in[7];
    const int*   src     = (const int*)d_in[8];
    const int*   dst     = (const int*)d_in[9];

    const int Nq = in_sizes[0] / HID;
    const int Ns = in_sizes[1] / HID;
    const int E  = in_sizes[8];
    float* out = (float*)d_out;

    // ---- workspace (~106 MB) ----
    float* q     = (float*)d_ws;                        // Ns*256 f32 (reused as o_pre)
    short* kv    = (short*)(q + (size_t)Ns * HID);      // Nq*512 bf16 (k|v interleaved)
    int* counts  = (int*)(kv + (size_t)Nq * 512);       // Ns   (reused: cursor, then WtO)
    int* offsets = counts + Ns;                         // Ns+1 (+pad)
    int* bsums   = offsets + Ns + 8;                    // 64
    int* slot    = bsums + 64;                          // E    (first 768KB doubles as WtQKV)
    short* WtQKV = (short*)slot;                        // 3 * 131072 shorts
    short* WtO   = (short*)counts;                      // 131072 shorts

    const dim3 blk(256);
    const int  gm = (Ns + 127) / 128;   // Ns == Nq == 50000
    const int  nb = (Ns + SCAN_B - 1) / SCAN_B;

    convw_kernel<<<768, blk, 0, stream>>>(Wq, Wk, Wv, WtQKV);
    gemm_mfma<<<gm, 512, 0, stream>>>(node,    WtQKV,          bq,      q,       nullptr, 0, Ns);
    gemm_mfma<<<gm, 512, 0, stream>>>(context, WtQKV + 131072, nullptr, nullptr, kv,      0, Nq);
    gemm_mfma<<<gm, 512, 0, stream>>>(context, WtQKV + 262144, nullptr, nullptr, kv,      1, Nq);

    zero_kernel<<<(Ns + 255) / 256, blk, 0, stream>>>(counts, Ns);
    histogram_kernel<<<(E + 255) / 256, blk, 0, stream>>>(dst, counts, E);
    scan_local<<<nb, SCAN_B, 0, stream>>>(counts, offsets, bsums, Ns);
    scan_bsums<<<1, 64, 0, stream>>>(bsums, offsets + Ns, nb);
    scan_add<<<nb, SCAN_B, 0, stream>>>(offsets, bsums, counts /*cursor*/, Ns);
    scatter_kernel<<<(E + 255) / 256, blk, 0, stream>>>(src, dst, counts /*cursor*/, slot, E);

    aggregate_kernel<<<(Ns + 3) / 4, blk, 0, stream>>>(q, kv, offsets, slot, q, Ns);

    convw_kernel<<<256, blk, 0, stream>>>(Wo, Wo, Wo, WtO);
    gemm_mfma<<<gm, 512, 0, stream>>>(q, WtO, bo, out, nullptr, 0, Ns);
}